// Round 8
// baseline (61.701 us; speedup 1.0000x reference)
//
#include <hip/hip_runtime.h>

// Subtraction2: out[n, c*49 + kh*7 + kw, h, w] = x1[n,c,h,w] - x2[n,c,refl(h+kh-3),refl(w+kw-3)]
// N=8 C=64 H=W=56 K=7 PAD=3 -> h_out=w_out=56, x1c == x1.
// Ladder: R1 63.9 -> R3 62.1 (window selects) -> R4 LDS 68.7 (reverted) -> R5 61.0 (XCD swz, null)
//         -> R6 60.7 (non-nt, null). Writes 315MB @5.2TB/s vs fill 6.9TB/s.
// R7: kill wave churn. Thread = (nc,h,w4), unrolled kh*kw -> 49 stores/thread (784B),
//     22 loads amortized. 6272 waves (was 45056), 1568 WGs (was 11264).

typedef float f4 __attribute__((ext_vector_type(4)));

constexpr int N_   = 8;
constexpr int C_   = 64;
constexpr int H_   = 56;
constexpr int W_   = 56;
constexpr int K_   = 7;
constexpr int PAD_ = 3;
constexpr int W4_  = W_ / 4;                  // 14
constexpr int HW_  = H_ * W_;                 // 3136 floats per plane
constexpr int SPC_ = H_ * W4_;                // sites per (n,c): 784
constexpr int TOT_ = N_ * C_ * SPC_;          // 401408 sites
constexpr int NBLK_ = TOT_ / 256;             // 1568 blocks exactly
constexpr int NXCD_ = 8;
constexpr int CPX_  = NBLK_ / NXCD_;          // 196

__device__ __forceinline__ int refl(int i) {
    i = (i < 0) ? -i : i;
    return (i < H_) ? i : (2 * (H_ - 1) - i);
}

__global__ __launch_bounds__(256)
void sub2_kernel(const float* __restrict__ x1,
                 const float* __restrict__ x2,
                 float* __restrict__ out)
{
    // Bijective XCD-chunk swizzle (1568 = 8*196): each XCD owns a contiguous output run.
    int bid = blockIdx.x;
    int wg  = (bid & (NXCD_ - 1)) * CPX_ + (bid >> 3);

    int t  = wg * 256 + threadIdx.x;          // site id, w4 fastest
    int w4 = t % W4_;
    int r  = t / W4_;
    int h  = r % H_;
    int nc = r / H_;                          // n*C_ + c

    const float* __restrict__ x1row = x1 + ((size_t)nc * H_ + h) * W_;
    const float* __restrict__ x2pl  = x2 + (size_t)nc * HW_;

    int w0 = w4 * 4;
    f4 a = *reinterpret_cast<const f4*>(x1row + w0);

    int wb = w0 - 4;
    wb = wb < 0 ? 0 : (wb > 44 ? 44 : wb);
    bool eL = (w4 == 0);
    bool eR = (w4 == W4_ - 1);

    constexpr int pL[10] = {3, 2, 1, 0, 1, 2, 3, 4, 5, 6};
    constexpr int pR[10] = {5, 6, 7, 8, 9, 10, 11, 10, 9, 8};

    float* __restrict__ oplane =
        out + ((size_t)nc * (K_ * K_)) * HW_ + h * W_ + w0;

#pragma unroll
    for (int kh = 0; kh < K_; ++kh) {
        int hs = refl(h + kh - PAD_);
        const float* xr = x2pl + hs * W_ + wb;
        f4 f0 = *reinterpret_cast<const f4*>(xr);
        f4 f1 = *reinterpret_cast<const f4*>(xr + 4);
        f4 f2 = *reinterpret_cast<const f4*>(xr + 8);
        float f[12] = {f0.x, f0.y, f0.z, f0.w, f1.x, f1.y, f1.z, f1.w,
                       f2.x, f2.y, f2.z, f2.w};

        float b[10];
#pragma unroll
        for (int j = 0; j < 10; ++j)
            b[j] = eL ? f[pL[j]] : (eR ? f[pR[j]] : f[j + 1]);

#pragma unroll
        for (int kw = 0; kw < K_; ++kw) {
            f4 v;
            v.x = a.x - b[kw + 0];
            v.y = a.y - b[kw + 1];
            v.z = a.z - b[kw + 2];
            v.w = a.w - b[kw + 3];
            *reinterpret_cast<f4*>(oplane + (size_t)(kh * K_ + kw) * HW_) = v;
        }
    }
}

extern "C" void kernel_launch(void* const* d_in, const int* in_sizes, int n_in,
                              void* d_out, int out_size, void* d_ws, size_t ws_size,
                              hipStream_t stream) {
    const float* x1 = (const float*)d_in[0];
    const float* x2 = (const float*)d_in[1];
    float* out = (float*)d_out;

    sub2_kernel<<<dim3(NBLK_), 256, 0, stream>>>(x1, x2, out);
}